// Round 1
// baseline (703.031 us; speedup 1.0000x reference)
//
#include <hip/hip_runtime.h>
#include <math.h>

// Problem constants (from reference): B=2, C=64, N=64, H=W=128, P=32, K=8
#define BB 2
#define CC 64
#define NN 64
#define HH 128
#define WW 128
#define PP 32
#define KK 8
#define HWSZ (HH * WW)   // 16384

// ---------------------------------------------------------------------------
// Kernel 1: per-(b,c,n) sum over H*W.  One block per slice, 256 threads,
// float4 loads (16 B/lane).  Streams the full 512 MB input -> HBM-bound.
// sums[(b*C + c)*N + n] = sum_hw x[b,c,n,h,w]
// ---------------------------------------------------------------------------
__global__ __launch_bounds__(256) void k_reduce_hw(const float* __restrict__ x,
                                                   float* __restrict__ sums) {
    const int bid = blockIdx.x;  // (b*C + c)*N + n, 0..8191
    const float4* __restrict__ src =
        reinterpret_cast<const float4*>(x + (size_t)bid * HWSZ);
    const int t = threadIdx.x;

    float acc = 0.0f;
#pragma unroll
    for (int j = 0; j < 16; ++j) {          // 16 * 256 * 4 = 16384 floats
        float4 v = src[t + j * 256];
        acc += (v.x + v.y) + (v.z + v.w);
    }
    // wave (64-lane) butterfly reduce
#pragma unroll
    for (int off = 32; off; off >>= 1) acc += __shfl_xor(acc, off);

    __shared__ float wsum[4];
    if ((t & 63) == 0) wsum[t >> 6] = acc;
    __syncthreads();
    if (t == 0) sums[bid] = (wsum[0] + wsum[1]) + (wsum[2] + wsum[3]);
}

// ---------------------------------------------------------------------------
// Kernel 2: scores -> softmax over N=64 -> top-8 (lowest-index tie-break,
// matching jax.lax.top_k).  One 64-lane wave per batch.
// score[b,n] = b_score + (0.5/HW) * sum_c w_score[c>>1] * sums[b,c,n]
// ---------------------------------------------------------------------------
__global__ __launch_bounds__(64) void k_score_topk(const float* __restrict__ sums,
                                                   const float* __restrict__ w_score,
                                                   const float* __restrict__ b_score,
                                                   int* __restrict__ topk_idx,
                                                   float* __restrict__ topk_val) {
    const int b = blockIdx.x;
    const int n = threadIdx.x;  // 0..63
    const float* __restrict__ S = sums + b * CC * NN;

    float acc = 0.0f;
#pragma unroll
    for (int c = 0; c < CC; ++c) acc += w_score[c >> 1] * S[c * NN + n];
    float score = acc * (0.5f / (float)HWSZ) + b_score[0];

    // softmax over the 64 lanes
    float m = score;
#pragma unroll
    for (int off = 32; off; off >>= 1) m = fmaxf(m, __shfl_xor(m, off));
    float e = expf(score - m);
    float s = e;
#pragma unroll
    for (int off = 32; off; off >>= 1) s += __shfl_xor(s, off);
    float w = e / s;

    // iterative top-8: butterfly argmax (value desc, index asc on ties)
    float v = w;
#pragma unroll
    for (int k = 0; k < KK; ++k) {
        float bv = v;
        int bi = n;
#pragma unroll
        for (int off = 32; off; off >>= 1) {
            float ov = __shfl_xor(bv, off);
            int oi = __shfl_xor(bi, off);
            if (ov > bv || (ov == bv && oi < bi)) { bv = ov; bi = oi; }
        }
        if (n == 0) {
            topk_idx[b * KK + k] = bi;
            topk_val[b * KK + k] = bv;
        }
        if (n == bi) v = -INFINITY;  // remove winner for next round
    }
}

// ---------------------------------------------------------------------------
// Kernel 3: gather the K winning slices, average channel pairs, scale by the
// softmax weight.  One block per (b,p,k) output slice; float4 in/out.
// out[b,p,k,h,w] = 0.5*(x[b,2p,n_k,h,w] + x[b,2p+1,n_k,h,w]) * val[b,k]
// ---------------------------------------------------------------------------
__global__ __launch_bounds__(256) void k_gather(const float* __restrict__ x,
                                                const int* __restrict__ topk_idx,
                                                const float* __restrict__ topk_val,
                                                float* __restrict__ out) {
    const int bid = blockIdx.x;       // ((b*P + p)*K + k), 0..511
    const int k = bid % KK;
    const int bp = bid / KK;
    const int p = bp % PP;
    const int b = bp / PP;

    const int n = topk_idx[b * KK + k];
    const float val = topk_val[b * KK + k] * 0.5f;

    const float4* __restrict__ s0 = reinterpret_cast<const float4*>(
        x + (((size_t)(b * CC + 2 * p)) * NN + n) * HWSZ);
    const float4* __restrict__ s1 = reinterpret_cast<const float4*>(
        x + (((size_t)(b * CC + 2 * p + 1)) * NN + n) * HWSZ);
    float4* __restrict__ o =
        reinterpret_cast<float4*>(out + (size_t)bid * HWSZ);

    const int t = threadIdx.x;
#pragma unroll
    for (int j = 0; j < 16; ++j) {
        float4 a = s0[t + j * 256];
        float4 c = s1[t + j * 256];
        float4 r;
        r.x = (a.x + c.x) * val;
        r.y = (a.y + c.y) * val;
        r.z = (a.z + c.z) * val;
        r.w = (a.w + c.w) * val;
        o[t + j * 256] = r;
    }
}

// ---------------------------------------------------------------------------
extern "C" void kernel_launch(void* const* d_in, const int* in_sizes, int n_in,
                              void* d_out, int out_size, void* d_ws, size_t ws_size,
                              hipStream_t stream) {
    const float* x       = (const float*)d_in[0];  // [B,C,N,H,W] fp32
    const float* w_score = (const float*)d_in[1];  // [1,P]
    const float* b_score = (const float*)d_in[2];  // [1]
    float* out = (float*)d_out;                    // [B,P,K,H,W] fp32

    // workspace layout
    float* sums     = (float*)d_ws;                      // B*C*N = 8192 floats
    int*   topk_idx = (int*)((char*)d_ws + BB * CC * NN * sizeof(float));
    float* topk_val = (float*)((char*)topk_idx + BB * KK * sizeof(int));

    k_reduce_hw<<<BB * CC * NN, 256, 0, stream>>>(x, sums);
    k_score_topk<<<BB, 64, 0, stream>>>(sums, w_score, b_score, topk_idx, topk_val);
    k_gather<<<BB * PP * KK, 256, 0, stream>>>(x, topk_idx, topk_val, out);
}